// Round 1
// baseline (331.513 us; speedup 1.0000x reference)
//
#include <hip/hip_runtime.h>
#include <math.h>
#include <stdint.h>

#define HH 480
#define WW 640
#define HW (HH*WW)
#define KK 512
#define DD 256
#define KP1 513
#define CAND_CAP 24576
#define SORTN 4096
#define NORM_F (-6.9314718055994531f)   /* -log(1024) */
#define LOGK_F (6.2383246250395077f)    /* log(512) */

// ---------------- ws layout (bytes) ----------------
#define OFF_OFFS   0u          /* 1024 int */
#define OFF_SCORE  4096u       /* 2 * HW f32 ; Z/ZT reuse this region later */
#define OFF_Z      4096u
#define OFF_ZT     (4096u + 1052928u)
#define OFF_SMOOTH 2461696u    /* 2 * HW f32 */
#define OFF_CAND   4919296u    /* 2 * CAND_CAP u64 */
#define OFF_HIST   5312512u    /* 2 * 65536 int */
#define OFF_CNT    5836800u    /* 2 int (+pad) -- contiguous after HIST for one memset */
#define OFF_KIDX   5837056u    /* 2 * 512 int */
#define OFF_DESC   5841152u    /* 2 * 512 * 256 f32 */
#define OFF_SBUF   6889728u    /* 2 * 512 f32 */
#define OFF_U      6893824u    /* 513 f32 */
#define OFF_V      6896128u    /* 513 f32 */

// ---------------------------------------------------------------------------
// MT19937(42) -> numpy RandomState.randint(-8,9,(256,4)) replication.
// Twist parallelized in 3 phases (deps: i<227 old-only; [227,454) needs new[i-227]
// from phase1; [454,624) needs new[i-227] from phase2; i=623 uses new[0]).
// Draw semantics: val = next_u32() & 31, reject while val > 16; out = val - 8.
// ---------------------------------------------------------------------------
__global__ __launch_bounds__(256) void gen_offsets_kernel(int* __restrict__ offs) {
  __shared__ unsigned int st[624], nx[624];
  __shared__ unsigned int outv[4992];
  __shared__ int csum[256];
  const int t = threadIdx.x;
  if (t == 0) {
    unsigned int x = 42u;
    st[0] = x;
    for (int i = 1; i < 624; ++i) { x = 1812433253u*(x ^ (x >> 30)) + (unsigned)i; st[i] = x; }
  }
  __syncthreads();
  for (int blk = 0; blk < 8; ++blk) {
    for (int i = t; i < 227; i += 256) {
      unsigned int y = (st[i] & 0x80000000u) | (st[i+1] & 0x7fffffffu);
      nx[i] = st[i+397] ^ (y >> 1) ^ ((y & 1u) ? 2567483615u : 0u);
    }
    __syncthreads();
    for (int i = 227 + t; i < 454; i += 256) {
      unsigned int y = (st[i] & 0x80000000u) | (st[i+1] & 0x7fffffffu);
      nx[i] = nx[i-227] ^ (y >> 1) ^ ((y & 1u) ? 2567483615u : 0u);
    }
    __syncthreads();
    for (int i = 454 + t; i < 624; i += 256) {
      unsigned int y;
      if (i < 623) y = (st[i] & 0x80000000u) | (st[i+1] & 0x7fffffffu);
      else         y = (st[623] & 0x80000000u) | (nx[0] & 0x7fffffffu);
      nx[i] = nx[i-227] ^ (y >> 1) ^ ((y & 1u) ? 2567483615u : 0u);
    }
    __syncthreads();
    for (int i = t; i < 624; i += 256) {
      unsigned int y = nx[i];
      y ^= y >> 11;
      y ^= (y << 7)  & 2636928640u;
      y ^= (y << 15) & 4022730752u;
      y ^= y >> 18;
      outv[blk*624 + i] = y;
      st[i] = nx[i];
    }
    __syncthreads();
  }
  // parallel rejection-compaction (order-preserving)
  const int base = t * 20;
  int cnt = 0;
  for (int e = 0; e < 20; ++e) {
    int i = base + e;
    if (i < 4992 && (outv[i] & 31u) <= 16u) cnt++;
  }
  csum[t] = cnt;
  __syncthreads();
  if (t == 0) {
    int run = 0;
    for (int i = 0; i < 256; ++i) { int tmp = csum[i]; csum[i] = run; run += tmp; }
  }
  __syncthreads();
  int pos = csum[t];
  for (int e = 0; e < 20; ++e) {
    int i = base + e;
    if (i < 4992) {
      unsigned int mv = outv[i] & 31u;
      if (mv <= 16u) { if (pos < 1024) offs[pos] = (int)mv - 8; pos++; }
    }
  }
}

// ---------------------------------------------------------------------------
// Fused detector: Sobel -> products -> 3x3 box -> min-eig score, plus 5x5 smooth.
// Zero padding for all convs (lax 'SAME'); products OUTSIDE the image are zero
// (reference box-filters the HxW product map with zero pad).
// Summation orders mirror conv (kh,kw) row-major with per-term weight multiply.
// ---------------------------------------------------------------------------
__global__ __launch_bounds__(256) void detector_kernel(const float* __restrict__ img0,
    const float* __restrict__ img1, float* __restrict__ score, float* __restrict__ smooth) {
  __shared__ float tile[20][20];
  __shared__ float pxx[18][18], pyy[18][18], pxy[18][18];
  const int imgI = blockIdx.z;
  const float* img = imgI ? img1 : img0;
  const int bx0 = blockIdx.x * 16, by0 = blockIdx.y * 16;
  const int tx = threadIdx.x, ty = threadIdx.y;
  const int lt = ty * 16 + tx;
  for (int p = lt; p < 400; p += 256) {
    int r = p / 20, c = p % 20;
    int gy = by0 - 2 + r, gx = bx0 - 2 + c;
    float v = 0.f;
    if (gy >= 0 && gy < HH && gx >= 0 && gx < WW) v = img[gy*WW + gx];
    tile[r][c] = v;
  }
  __syncthreads();
  for (int p = lt; p < 324; p += 256) {
    int r = p / 18, c = p % 18;
    int gy = by0 - 1 + r, gx = bx0 - 1 + c;
    float vxx = 0.f, vyy = 0.f, vxy = 0.f;
    if (gy >= 0 && gy < HH && gx >= 0 && gx < WW) {
      float t00 = tile[r][c],   t01 = tile[r][c+1],   t02 = tile[r][c+2];
      float t10 = tile[r+1][c],                        t12 = tile[r+1][c+2];
      float t20 = tile[r+2][c], t21 = tile[r+2][c+1], t22 = tile[r+2][c+2];
      float ix = t00*(-1.f) + t02*1.f + t10*(-2.f) + t12*2.f + t20*(-1.f) + t22*1.f;
      float iy = t00*(-1.f) + t01*(-2.f) + t02*(-1.f) + t20*1.f + t21*2.f + t22*1.f;
      vxx = ix*ix; vyy = iy*iy; vxy = ix*iy;
    }
    pxx[r][c] = vxx; pyy[r][c] = vyy; pxy[r][c] = vxy;
  }
  __syncthreads();
  const float c9 = 1.f/9.f, c25 = 1.f/25.f;
  float sxx = 0.f, syy = 0.f, sxy = 0.f;
  for (int r = 0; r < 3; ++r)
    for (int c = 0; c < 3; ++c) {
      sxx += pxx[ty+r][tx+c] * c9;
      syy += pyy[ty+r][tx+c] * c9;
      sxy += pxy[ty+r][tx+c] * c9;
    }
  float tdif = sxx - syy;
  float disc = tdif*tdif + 4.f*(sxy*sxy) + 1e-12f;
  float sc = 0.5f * ((sxx + syy) - sqrtf(disc));
  float sm = 0.f;
  for (int r = 0; r < 5; ++r)
    for (int c = 0; c < 5; ++c)
      sm += tile[ty+r][tx+c] * c25;
  int y = by0 + ty, x = bx0 + tx;
  score [imgI*HW + y*WW + x] = sc;
  smooth[imgI*HW + y*WW + x] = sm;
}

// ---------------------------------------------------------------------------
// 7x7 NMS; candidates -> (orderedScore<<32 | ~idx) keys + 16-bit-bin histogram
// ---------------------------------------------------------------------------
__global__ __launch_bounds__(256) void nms_kernel(const float* __restrict__ score,
    unsigned long long* __restrict__ cand, int* __restrict__ cnt, int* __restrict__ hist) {
  __shared__ float t[22][22];
  const int imgI = blockIdx.z;
  const float* s = score + imgI*HW;
  const int bx0 = blockIdx.x*16, by0 = blockIdx.y*16;
  const int tx = threadIdx.x, ty = threadIdx.y, lt = ty*16+tx;
  for (int p = lt; p < 484; p += 256) {
    int r = p/22, c = p%22;
    int gy = by0-3+r, gx = bx0-3+c;
    t[r][c] = (gy >= 0 && gy < HH && gx >= 0 && gx < WW) ? s[gy*WW+gx] : -INFINITY;
  }
  __syncthreads();
  float cv = t[ty+3][tx+3];
  float m = -INFINITY;
  for (int r = 0; r < 7; ++r)
    for (int c = 0; c < 7; ++c)
      m = fmaxf(m, t[ty+r][tx+c]);
  if (cv >= m && cv > 0.f) {
    int idx = (by0+ty)*WW + (bx0+tx);
    unsigned int ub = __float_as_uint(cv) | 0x80000000u;  // score > 0
    unsigned long long key = ((unsigned long long)ub << 32) | (unsigned int)(~idx);
    int pos = atomicAdd(cnt + imgI, 1);
    if (pos < CAND_CAP) cand[(size_t)imgI*CAND_CAP + pos] = key;
    atomicAdd(hist + imgI*65536 + (int)(ub >> 16), 1);
  }
}

// ---------------------------------------------------------------------------
// Single-block top-512 (sorted): histogram threshold -> <=4096 survivors ->
// LDS bitonic sort desc -> kpts (float y,x) + kidx
// ---------------------------------------------------------------------------
__global__ __launch_bounds__(1024) void select_kernel(const unsigned long long* __restrict__ cand,
    const int* __restrict__ cnt, const int* __restrict__ hist,
    float* __restrict__ kptsOut, int* __restrict__ kidx) {
  __shared__ unsigned long long sk[SORTN];
  __shared__ int chunkSum[1024];
  __shared__ int sBstar, sCount;
  const int imgI = blockIdx.x;
  const int t = threadIdx.x;
  const int* h = hist + imgI*65536;
  int sum = 0;
  for (int k = 0; k < 64; ++k) sum += h[t*64 + k];
  chunkSum[t] = sum;
  if (t == 0) { sCount = 0; sBstar = 0; }
  __syncthreads();
  if (t == 0) {
    int acc = 0;
    for (int c = 1023; c >= 0; --c) {
      if (acc + chunkSum[c] >= KK) {
        int b = c*64 + 63;
        for (;; --b) { acc += h[b]; if (acc >= KK) break; }
        sBstar = b;
        break;
      }
      acc += chunkSum[c];
    }
  }
  __syncthreads();
  const int bstar = sBstar;
  int M = cnt[imgI]; if (M > CAND_CAP) M = CAND_CAP;
  for (int i = t; i < M; i += 1024) {
    unsigned long long key = cand[(size_t)imgI*CAND_CAP + i];
    int bin = (int)(key >> 48);
    if (bin >= bstar) {
      int pos = atomicAdd(&sCount, 1);
      if (pos < SORTN) sk[pos] = key;
    }
  }
  __syncthreads();
  int cs = sCount; if (cs > SORTN) cs = SORTN;
  for (int i = t; i < SORTN; i += 1024) if (i >= cs) sk[i] = 0ull;
  __syncthreads();
  for (int k = 2; k <= SORTN; k <<= 1) {
    for (int j = k >> 1; j > 0; j >>= 1) {
      for (int i = t; i < SORTN; i += 1024) {
        int ixj = i ^ j;
        if (ixj > i) {
          unsigned long long a = sk[i], b = sk[ixj];
          if (((i & k) == 0) == (a < b)) { sk[i] = b; sk[ixj] = a; }
        }
      }
      __syncthreads();
    }
  }
  if (t < KK) {
    unsigned long long key = sk[t];
    float y = -1.f, x = -1.f;
    int id = -1;
    if (key != 0ull) {
      id = (int)(~(unsigned int)(key & 0xFFFFFFFFull));
      y = (float)(id / WW);
      x = (float)(id % WW);
    }
    kptsOut[imgI*2*KK + 2*t]     = y;
    kptsOut[imgI*2*KK + 2*t + 1] = x;
    kidx[imgI*KK + t] = id;
  }
}

// ---------------------------------------------------------------------------
// Per-keypoint BAD descriptor (edge-clamped gathers on smooth) + L2 norm + s
// ---------------------------------------------------------------------------
__global__ __launch_bounds__(256) void desc_kernel(const float* __restrict__ smooth,
    const int* __restrict__ kidx, const int* __restrict__ offs,
    float* __restrict__ desc, float* __restrict__ sbuf) {
  __shared__ float wsum[4];
  const int k = blockIdx.x, imgI = blockIdx.y;
  const int j = threadIdx.x;
  const int id = kidx[imgI*KK + k];
  float val = 0.f;
  if (id >= 0) {
    int y = id / WW, x = id % WW;
    int o0 = offs[4*j], o1 = offs[4*j+1], o2 = offs[4*j+2], o3 = offs[4*j+3];
    const float* sm = smooth + imgI*HW;
    int ya = min(max(y+o0, 0), HH-1), xa = min(max(x+o1, 0), WW-1);
    int yb = min(max(y+o2, 0), HH-1), xb = min(max(x+o3, 0), WW-1);
    val = sm[ya*WW + xa] - sm[yb*WW + xb];
  }
  float ss = val*val;
  for (int off = 32; off; off >>= 1) ss += __shfl_down(ss, off);
  if ((j & 63) == 0) wsum[j >> 6] = ss;
  __syncthreads();
  if (j == 0) wsum[0] = wsum[0] + wsum[1] + wsum[2] + wsum[3];
  __syncthreads();
  float tot = wsum[0];
  float inv = 1.f / (sqrtf(tot) + 1e-12f);
  desc[((size_t)imgI*KK + k)*DD + j] = val * inv;
  if (j == 0) sbuf[imgI*KK + k] = tot * inv * inv;
}

// ---------------------------------------------------------------------------
// Z = -sqrt(clip(s1+s2-2*d1.d2, 1e-12)); dustbins = 1.0; also write Z^T
// ---------------------------------------------------------------------------
__global__ __launch_bounds__(256) void zbuild_kernel(const float* __restrict__ desc,
    const float* __restrict__ sbuf, float* __restrict__ Z, float* __restrict__ ZT) {
  __shared__ float sA[16][260], sB[16][260];
  const int ty = threadIdx.y, tx = threadIdx.x;
  const int i0 = blockIdx.y*16, j0 = blockIdx.x*16;
  const int lt = ty*16 + tx;
  for (int p = lt; p < 16*DD; p += 256) {
    int r = p / DD, c = p % DD;
    sA[r][c] = (i0 + r < KK) ? desc[((size_t)0*KK + i0 + r)*DD + c] : 0.f;
    sB[r][c] = (j0 + r < KK) ? desc[((size_t)1*KK + j0 + r)*DD + c] : 0.f;
  }
  __syncthreads();
  const int i = i0 + ty, j = j0 + tx;
  if (i > KK || j > KK) return;
  if (i < KK && j < KK) {
    float acc = 0.f;
    for (int c = 0; c < DD; ++c) acc += sA[ty][c] * sB[tx][c];
    float d2 = sbuf[0*KK + i] + sbuf[1*KK + j] - 2.f*acc;
    float dist = sqrtf(fmaxf(d2, 1e-12f));
    Z [i*KP1 + j] = -dist;
    ZT[j*KP1 + i] = -dist;
  } else {
    Z [i*KP1 + j] = 1.0f;
    ZT[j*KP1 + i] = 1.0f;
  }
}

// ---------------------------------------------------------------------------
// One Sinkhorn half-step: out[i] = log_mu(i) - logsumexp_j(Zm[i,:] + addv[:])
// (used for both u and v updates; Zm is Z or Z^T)
// ---------------------------------------------------------------------------
__global__ __launch_bounds__(256) void lse_kernel(const float* __restrict__ Zm,
    const float* __restrict__ addv, float* __restrict__ outv) {
  __shared__ float red[4];
  const int i = blockIdx.x, t = threadIdx.x;
  const float* row = Zm + (size_t)i*KP1;
  float a0 = row[t] + addv[t];
  float a1 = row[t+256] + addv[t+256];
  float a2 = -INFINITY;
  if (t == 0) a2 = row[512] + addv[512];
  float m = fmaxf(a0, fmaxf(a1, a2));
  for (int off = 32; off; off >>= 1) m = fmaxf(m, __shfl_xor(m, off));
  if ((t & 63) == 0) red[t >> 6] = m;
  __syncthreads();
  float bm = fmaxf(fmaxf(red[0], red[1]), fmaxf(red[2], red[3]));
  __syncthreads();
  float s = expf(a0 - bm) + expf(a1 - bm) + expf(a2 - bm);  // exp(-inf)=0
  for (int off = 32; off; off >>= 1) s += __shfl_xor(s, off);
  if ((t & 63) == 0) red[t >> 6] = s;
  __syncthreads();
  if (t == 0) {
    float S = red[0] + red[1] + red[2] + red[3];
    float logmu = (i < KK) ? NORM_F : (LOGK_F + NORM_F);
    outv[i] = logmu - (logf(S) + bm);
  }
}

__global__ __launch_bounds__(256) void prob_kernel(const float* __restrict__ Z,
    const float* __restrict__ u, const float* __restrict__ v, float* __restrict__ out) {
  const int i = blockIdx.x, t = threadIdx.x;
  const float ui = u[i];
  for (int j = t; j < KP1; j += 256)
    out[(size_t)i*KP1 + j] = expf(Z[(size_t)i*KP1 + j] + ui + v[j] - NORM_F);
}

extern "C" void kernel_launch(void* const* d_in, const int* in_sizes, int n_in,
                              void* d_out, int out_size, void* d_ws, size_t ws_size,
                              hipStream_t stream) {
  const float* img1 = (const float*)d_in[0];
  const float* img2 = (const float*)d_in[1];
  float* out = (float*)d_out;
  char* ws = (char*)d_ws;

  int*   offs   = (int*)  (ws + OFF_OFFS);
  float* score  = (float*)(ws + OFF_SCORE);
  float* smooth = (float*)(ws + OFF_SMOOTH);
  unsigned long long* cand = (unsigned long long*)(ws + OFF_CAND);
  int*   cnt    = (int*)  (ws + OFF_CNT);
  int*   hist   = (int*)  (ws + OFF_HIST);
  int*   kidx   = (int*)  (ws + OFF_KIDX);
  float* desc   = (float*)(ws + OFF_DESC);
  float* sbuf   = (float*)(ws + OFF_SBUF);
  float* Z      = (float*)(ws + OFF_Z);     // aliases SCORE region (score dead by then)
  float* ZT     = (float*)(ws + OFF_ZT);
  float* ubuf   = (float*)(ws + OFF_U);
  float* vbuf   = (float*)(ws + OFF_V);

  hipMemsetAsync(ws + OFF_HIST, 0, 524288 + 256, stream);   // hist + counters
  hipMemsetAsync(ws + OFF_V, 0, KP1 * sizeof(float), stream);

  gen_offsets_kernel<<<1, 256, 0, stream>>>(offs);
  detector_kernel<<<dim3(40, 30, 2), dim3(16, 16), 0, stream>>>(img1, img2, score, smooth);
  nms_kernel<<<dim3(40, 30, 2), dim3(16, 16), 0, stream>>>(score, cand, cnt, hist);
  select_kernel<<<2, 1024, 0, stream>>>(cand, cnt, hist, out, kidx);
  desc_kernel<<<dim3(KK, 2), 256, 0, stream>>>(smooth, kidx, offs, desc, sbuf);
  zbuild_kernel<<<dim3(33, 33), dim3(16, 16), 0, stream>>>(desc, sbuf, Z, ZT);
  for (int it = 0; it < 20; ++it) {
    lse_kernel<<<KP1, 256, 0, stream>>>(Z,  vbuf, ubuf);   // u update (rows)
    lse_kernel<<<KP1, 256, 0, stream>>>(ZT, ubuf, vbuf);   // v update (cols)
  }
  prob_kernel<<<KP1, 256, 0, stream>>>(Z, ubuf, vbuf, out + 2*KK*2);
}

// Round 2
// 227.431 us; speedup vs baseline: 1.4576x; 1.4576x over previous
//
#include <hip/hip_runtime.h>
#include <math.h>
#include <stdint.h>

#define HH 480
#define WW 640
#define HW (HH*WW)
#define KK 512
#define DD 256
#define KP1 513
#define NSLOT 32
#define NBX 40
#define NBY 30
#define SLOTS_PER_IMG (NBX*NBY*NSLOT)   /* 38400 */
#define SORTN 4096
#define NORM_F (-6.9314718055994531f)   /* -log(1024) */
#define LOGK_F (6.2383246250395077f)    /* log(512) */

// ---------------- ws layout (bytes) ----------------
#define OFF_OFFS   0u          /* 1024 int */
#define OFF_SCORE  4096u       /* 2 * HW f32 ; Z/ZT alias this region (score dead after nms) */
#define OFF_Z      4096u
#define OFF_ZT     (4096u + 1052928u)
#define OFF_SMOOTH 2461696u    /* 2 * HW f32 */
#define OFF_CAND   4919296u    /* 2 * 38400 u64 = 614400 */
#define OFF_KIDX   5533696u    /* 2 * 512 int */
#define OFF_DESC   5537792u    /* 2 * 512 * 256 f32 */
#define OFF_SBUF   6586368u    /* 2 * 512 f32 */
#define OFF_U      6590464u    /* 513 f32 */
#define OFF_V      6592768u    /* 513 f32 */

// ---------------------------------------------------------------------------
// MT19937(42) -> numpy RandomState.randint(-8,9,(256,4)) replication.
// ---------------------------------------------------------------------------
__global__ __launch_bounds__(256) void gen_offsets_kernel(int* __restrict__ offs) {
  __shared__ unsigned int st[624], nx[624];
  __shared__ unsigned int outv[4992];
  __shared__ int csum[256];
  const int t = threadIdx.x;
  if (t == 0) {
    unsigned int x = 42u;
    st[0] = x;
    for (int i = 1; i < 624; ++i) { x = 1812433253u*(x ^ (x >> 30)) + (unsigned)i; st[i] = x; }
  }
  __syncthreads();
  for (int blk = 0; blk < 8; ++blk) {
    for (int i = t; i < 227; i += 256) {
      unsigned int y = (st[i] & 0x80000000u) | (st[i+1] & 0x7fffffffu);
      nx[i] = st[i+397] ^ (y >> 1) ^ ((y & 1u) ? 2567483615u : 0u);
    }
    __syncthreads();
    for (int i = 227 + t; i < 454; i += 256) {
      unsigned int y = (st[i] & 0x80000000u) | (st[i+1] & 0x7fffffffu);
      nx[i] = nx[i-227] ^ (y >> 1) ^ ((y & 1u) ? 2567483615u : 0u);
    }
    __syncthreads();
    for (int i = 454 + t; i < 624; i += 256) {
      unsigned int y;
      if (i < 623) y = (st[i] & 0x80000000u) | (st[i+1] & 0x7fffffffu);
      else         y = (st[623] & 0x80000000u) | (nx[0] & 0x7fffffffu);
      nx[i] = nx[i-227] ^ (y >> 1) ^ ((y & 1u) ? 2567483615u : 0u);
    }
    __syncthreads();
    for (int i = t; i < 624; i += 256) {
      unsigned int y = nx[i];
      y ^= y >> 11;
      y ^= (y << 7)  & 2636928640u;
      y ^= (y << 15) & 4022730752u;
      y ^= y >> 18;
      outv[blk*624 + i] = y;
      st[i] = nx[i];
    }
    __syncthreads();
  }
  const int base = t * 20;
  int cnt = 0;
  for (int e = 0; e < 20; ++e) {
    int i = base + e;
    if (i < 4992 && (outv[i] & 31u) <= 16u) cnt++;
  }
  csum[t] = cnt;
  __syncthreads();
  if (t == 0) {
    int run = 0;
    for (int i = 0; i < 256; ++i) { int tmp = csum[i]; csum[i] = run; run += tmp; }
  }
  __syncthreads();
  int pos = csum[t];
  for (int e = 0; e < 20; ++e) {
    int i = base + e;
    if (i < 4992) {
      unsigned int mv = outv[i] & 31u;
      if (mv <= 16u) { if (pos < 1024) offs[pos] = (int)mv - 8; pos++; }
    }
  }
}

// ---------------------------------------------------------------------------
// Fused detector: Sobel -> products -> 3x3 box -> min-eig score, plus 5x5 smooth.
// ---------------------------------------------------------------------------
__global__ __launch_bounds__(256) void detector_kernel(const float* __restrict__ img0,
    const float* __restrict__ img1, float* __restrict__ score, float* __restrict__ smooth) {
  __shared__ float tile[20][20];
  __shared__ float pxx[18][18], pyy[18][18], pxy[18][18];
  const int imgI = blockIdx.z;
  const float* img = imgI ? img1 : img0;
  const int bx0 = blockIdx.x * 16, by0 = blockIdx.y * 16;
  const int tx = threadIdx.x, ty = threadIdx.y;
  const int lt = ty * 16 + tx;
  for (int p = lt; p < 400; p += 256) {
    int r = p / 20, c = p % 20;
    int gy = by0 - 2 + r, gx = bx0 - 2 + c;
    float v = 0.f;
    if (gy >= 0 && gy < HH && gx >= 0 && gx < WW) v = img[gy*WW + gx];
    tile[r][c] = v;
  }
  __syncthreads();
  for (int p = lt; p < 324; p += 256) {
    int r = p / 18, c = p % 18;
    int gy = by0 - 1 + r, gx = bx0 - 1 + c;
    float vxx = 0.f, vyy = 0.f, vxy = 0.f;
    if (gy >= 0 && gy < HH && gx >= 0 && gx < WW) {
      float t00 = tile[r][c],   t01 = tile[r][c+1],   t02 = tile[r][c+2];
      float t10 = tile[r+1][c],                        t12 = tile[r+1][c+2];
      float t20 = tile[r+2][c], t21 = tile[r+2][c+1], t22 = tile[r+2][c+2];
      float ix = t00*(-1.f) + t02*1.f + t10*(-2.f) + t12*2.f + t20*(-1.f) + t22*1.f;
      float iy = t00*(-1.f) + t01*(-2.f) + t02*(-1.f) + t20*1.f + t21*2.f + t22*1.f;
      vxx = ix*ix; vyy = iy*iy; vxy = ix*iy;
    }
    pxx[r][c] = vxx; pyy[r][c] = vyy; pxy[r][c] = vxy;
  }
  __syncthreads();
  const float c9 = 1.f/9.f, c25 = 1.f/25.f;
  float sxx = 0.f, syy = 0.f, sxy = 0.f;
  for (int r = 0; r < 3; ++r)
    for (int c = 0; c < 3; ++c) {
      sxx += pxx[ty+r][tx+c] * c9;
      syy += pyy[ty+r][tx+c] * c9;
      sxy += pxy[ty+r][tx+c] * c9;
    }
  float tdif = sxx - syy;
  float disc = tdif*tdif + 4.f*(sxy*sxy) + 1e-12f;
  float sc = 0.5f * ((sxx + syy) - sqrtf(disc));
  float sm = 0.f;
  for (int r = 0; r < 5; ++r)
    for (int c = 0; c < 5; ++c)
      sm += tile[ty+r][tx+c] * c25;
  int y = by0 + ty, x = bx0 + tx;
  score [imgI*HW + y*WW + x] = sc;
  smooth[imgI*HW + y*WW + x] = sm;
}

// ---------------------------------------------------------------------------
// 7x7 NMS -> per-block slot compaction (NO global atomics).
// Each block owns NSLOT slots; winners (Chebyshev spacing >= 4 -> <=16/tile)
// compacted via ballot prefix; remaining slots zeroed. Key = score|~idx.
// ---------------------------------------------------------------------------
__global__ __launch_bounds__(256) void nms_kernel(const float* __restrict__ score,
    unsigned long long* __restrict__ cand) {
  __shared__ float t[22][22];
  __shared__ int wsum[4];
  __shared__ int wbase[4];
  const int imgI = blockIdx.z;
  const float* s = score + imgI*HW;
  const int bx0 = blockIdx.x*16, by0 = blockIdx.y*16;
  const int tx = threadIdx.x, ty = threadIdx.y, lt = ty*16+tx;
  for (int p = lt; p < 484; p += 256) {
    int r = p/22, c = p%22;
    int gy = by0-3+r, gx = bx0-3+c;
    t[r][c] = (gy >= 0 && gy < HH && gx >= 0 && gx < WW) ? s[gy*WW+gx] : -INFINITY;
  }
  __syncthreads();
  float cv = t[ty+3][tx+3];
  float m = -INFINITY;
  for (int r = 0; r < 7; ++r)
    for (int c = 0; c < 7; ++c)
      m = fmaxf(m, t[ty+r][tx+c]);
  bool pred = (cv >= m && cv > 0.f);
  unsigned long long mask = __ballot(pred);
  int lane = lt & 63, wid = lt >> 6;
  if (lane == 0) wsum[wid] = __popcll(mask);
  __syncthreads();
  if (lt == 0) {
    int s0 = wsum[0], s1 = wsum[1], s2 = wsum[2], s3 = wsum[3];
    wbase[0] = 0; wbase[1] = s0; wbase[2] = s0+s1; wbase[3] = s0+s1+s2;
    wsum[0] = s0+s1+s2+s3;   // total
  }
  __syncthreads();
  const int total = wsum[0];
  const size_t slotBase = (size_t)imgI*SLOTS_PER_IMG + (size_t)(blockIdx.y*NBX + blockIdx.x)*NSLOT;
  if (pred) {
    int pos = wbase[wid] + __popcll(mask & ((1ull << lane) - 1ull));
    if (pos < NSLOT) {
      int idx = (by0+ty)*WW + (bx0+tx);
      unsigned int ub = __float_as_uint(cv) | 0x80000000u;  // cv > 0 -> sign bit free
      cand[slotBase + pos] = ((unsigned long long)ub << 32) | (unsigned int)(~idx);
    }
  }
  if (lt >= total && lt < NSLOT) cand[slotBase + lt] = 0ull;
}

// ---------------------------------------------------------------------------
// Top-512 sorted select: two-level (10+10 bit) LDS histogram radix threshold
// over the 38400 slots, then dynamic-size LDS bitonic sort (desc).
// ---------------------------------------------------------------------------
__global__ __launch_bounds__(1024) void select_kernel(const unsigned long long* __restrict__ cand,
    float* __restrict__ kptsOut, int* __restrict__ kidx) {
  __shared__ unsigned long long sk[SORTN];
  __shared__ int hist[1024];
  __shared__ int sB1, sB2, sNeed, sCount;
  const int imgI = blockIdx.x;
  const int t = threadIdx.x;
  const unsigned long long* cd = cand + (size_t)imgI*SLOTS_PER_IMG;

  // --- level-1 histogram: key top 10 bits ---
  hist[t] = 0;
  if (t == 0) { sB1 = -1; sB2 = 0; sCount = 0; }
  __syncthreads();
  for (int i = t; i < SLOTS_PER_IMG; i += 1024) {
    unsigned long long k = cd[i];
    if (k) atomicAdd(&hist[(int)(k >> 54)], 1);
  }
  __syncthreads();
  for (int d = 1; d < 1024; d <<= 1) {            // suffix scan
    int v = hist[t] + ((t + d < 1024) ? hist[t + d] : 0);
    __syncthreads();
    hist[t] = v;
    __syncthreads();
  }
  if (hist[t] >= KK) atomicMax(&sB1, t);
  __syncthreads();
  const int b1 = sB1;                              // -1 => fewer than KK candidates
  if (t == 0 && b1 >= 0) {
    int above = (b1 < 1023) ? hist[b1 + 1] : 0;
    sNeed = KK - above;
  }
  __syncthreads();
  int b2 = 0;
  if (b1 >= 0) {
    // --- level-2 histogram: next 10 bits, within bin b1 ---
    hist[t] = 0;
    __syncthreads();
    for (int i = t; i < SLOTS_PER_IMG; i += 1024) {
      unsigned long long k = cd[i];
      if (k && (int)(k >> 54) == b1) atomicAdd(&hist[(int)(k >> 44) & 1023], 1);
    }
    __syncthreads();
    for (int d = 1; d < 1024; d <<= 1) {
      int v = hist[t] + ((t + d < 1024) ? hist[t + d] : 0);
      __syncthreads();
      hist[t] = v;
      __syncthreads();
    }
    if (hist[t] >= sNeed) atomicMax(&sB2, t);
    __syncthreads();
    b2 = sB2;
  }
  // --- compact survivors into sk ---
  for (int i = t; i < SLOTS_PER_IMG; i += 1024) {
    unsigned long long k = cd[i];
    if (k) {
      int bin1 = (int)(k >> 54);
      if (bin1 > b1 || (bin1 == b1 && ((int)(k >> 44) & 1023) >= b2)) {
        int pos = atomicAdd(&sCount, 1);
        if (pos < SORTN) sk[pos] = k;
      }
    }
  }
  __syncthreads();
  int cs = sCount; if (cs > SORTN) cs = SORTN;
  int n = KK;                                      // sort size: pow2 >= max(cs, 512)
  while (n < cs) n <<= 1;
  for (int i = t; i < n; i += 1024) if (i >= cs) sk[i] = 0ull;
  __syncthreads();
  for (int k = 2; k <= n; k <<= 1) {
    for (int j = k >> 1; j > 0; j >>= 1) {
      for (int i = t; i < n; i += 1024) {
        int ixj = i ^ j;
        if (ixj > i) {
          unsigned long long a = sk[i], b = sk[ixj];
          if (((i & k) == 0) == (a < b)) { sk[i] = b; sk[ixj] = a; }
        }
      }
      __syncthreads();
    }
  }
  if (t < KK) {
    unsigned long long key = sk[t];
    float y = -1.f, x = -1.f;
    int id = -1;
    if (key != 0ull) {
      id = (int)(~(unsigned int)(key & 0xFFFFFFFFull));
      y = (float)(id / WW);
      x = (float)(id % WW);
    }
    kptsOut[imgI*2*KK + 2*t]     = y;
    kptsOut[imgI*2*KK + 2*t + 1] = x;
    kidx[imgI*KK + t] = id;
  }
}

// ---------------------------------------------------------------------------
// Per-keypoint BAD descriptor (edge-clamped gathers on smooth) + L2 norm + s
// ---------------------------------------------------------------------------
__global__ __launch_bounds__(256) void desc_kernel(const float* __restrict__ smooth,
    const int* __restrict__ kidx, const int* __restrict__ offs,
    float* __restrict__ desc, float* __restrict__ sbuf) {
  __shared__ float wsum[4];
  const int k = blockIdx.x, imgI = blockIdx.y;
  const int j = threadIdx.x;
  const int id = kidx[imgI*KK + k];
  float val = 0.f;
  if (id >= 0) {
    int y = id / WW, x = id % WW;
    int o0 = offs[4*j], o1 = offs[4*j+1], o2 = offs[4*j+2], o3 = offs[4*j+3];
    const float* sm = smooth + imgI*HW;
    int ya = min(max(y+o0, 0), HH-1), xa = min(max(x+o1, 0), WW-1);
    int yb = min(max(y+o2, 0), HH-1), xb = min(max(x+o3, 0), WW-1);
    val = sm[ya*WW + xa] - sm[yb*WW + xb];
  }
  float ss = val*val;
  for (int off = 32; off; off >>= 1) ss += __shfl_down(ss, off);
  if ((j & 63) == 0) wsum[j >> 6] = ss;
  __syncthreads();
  if (j == 0) wsum[0] = wsum[0] + wsum[1] + wsum[2] + wsum[3];
  __syncthreads();
  float tot = wsum[0];
  float inv = 1.f / (sqrtf(tot) + 1e-12f);
  desc[((size_t)imgI*KK + k)*DD + j] = val * inv;
  if (j == 0) sbuf[imgI*KK + k] = tot * inv * inv;
}

// ---------------------------------------------------------------------------
// Z = -sqrt(clip(s1+s2-2*d1.d2, 1e-12)); dustbins = 1.0; also write Z^T
// ---------------------------------------------------------------------------
__global__ __launch_bounds__(256) void zbuild_kernel(const float* __restrict__ desc,
    const float* __restrict__ sbuf, float* __restrict__ Z, float* __restrict__ ZT) {
  __shared__ float sA[16][260], sB[16][260];
  const int ty = threadIdx.y, tx = threadIdx.x;
  const int i0 = blockIdx.y*16, j0 = blockIdx.x*16;
  const int lt = ty*16 + tx;
  for (int p = lt; p < 16*DD; p += 256) {
    int r = p / DD, c = p % DD;
    sA[r][c] = (i0 + r < KK) ? desc[((size_t)0*KK + i0 + r)*DD + c] : 0.f;
    sB[r][c] = (j0 + r < KK) ? desc[((size_t)1*KK + j0 + r)*DD + c] : 0.f;
  }
  __syncthreads();
  const int i = i0 + ty, j = j0 + tx;
  if (i > KK || j > KK) return;
  if (i < KK && j < KK) {
    float acc = 0.f;
    for (int c = 0; c < DD; ++c) acc += sA[ty][c] * sB[tx][c];
    float d2 = sbuf[0*KK + i] + sbuf[1*KK + j] - 2.f*acc;
    float dist = sqrtf(fmaxf(d2, 1e-12f));
    Z [i*KP1 + j] = -dist;
    ZT[j*KP1 + i] = -dist;
  } else {
    Z [i*KP1 + j] = 1.0f;
    ZT[j*KP1 + i] = 1.0f;
  }
}

// ---------------------------------------------------------------------------
// One Sinkhorn half-step: out[i] = log_mu(i) - logsumexp_j(Zm[i,:] + addv[:])
// ---------------------------------------------------------------------------
__global__ __launch_bounds__(256) void lse_kernel(const float* __restrict__ Zm,
    const float* __restrict__ addv, float* __restrict__ outv) {
  __shared__ float red[4];
  const int i = blockIdx.x, t = threadIdx.x;
  const float* row = Zm + (size_t)i*KP1;
  float a0 = row[t] + addv[t];
  float a1 = row[t+256] + addv[t+256];
  float a2 = -INFINITY;
  if (t == 0) a2 = row[512] + addv[512];
  float m = fmaxf(a0, fmaxf(a1, a2));
  for (int off = 32; off; off >>= 1) m = fmaxf(m, __shfl_xor(m, off));
  if ((t & 63) == 0) red[t >> 6] = m;
  __syncthreads();
  float bm = fmaxf(fmaxf(red[0], red[1]), fmaxf(red[2], red[3]));
  __syncthreads();
  float s = expf(a0 - bm) + expf(a1 - bm) + expf(a2 - bm);  // exp(-inf)=0
  for (int off = 32; off; off >>= 1) s += __shfl_xor(s, off);
  if ((t & 63) == 0) red[t >> 6] = s;
  __syncthreads();
  if (t == 0) {
    float S = red[0] + red[1] + red[2] + red[3];
    float logmu = (i < KK) ? NORM_F : (LOGK_F + NORM_F);
    outv[i] = logmu - (logf(S) + bm);
  }
}

__global__ __launch_bounds__(256) void prob_kernel(const float* __restrict__ Z,
    const float* __restrict__ u, const float* __restrict__ v, float* __restrict__ out) {
  const int i = blockIdx.x, t = threadIdx.x;
  const float ui = u[i];
  for (int j = t; j < KP1; j += 256)
    out[(size_t)i*KP1 + j] = expf(Z[(size_t)i*KP1 + j] + ui + v[j] - NORM_F);
}

extern "C" void kernel_launch(void* const* d_in, const int* in_sizes, int n_in,
                              void* d_out, int out_size, void* d_ws, size_t ws_size,
                              hipStream_t stream) {
  const float* img1 = (const float*)d_in[0];
  const float* img2 = (const float*)d_in[1];
  float* out = (float*)d_out;
  char* ws = (char*)d_ws;

  int*   offs   = (int*)  (ws + OFF_OFFS);
  float* score  = (float*)(ws + OFF_SCORE);
  float* smooth = (float*)(ws + OFF_SMOOTH);
  unsigned long long* cand = (unsigned long long*)(ws + OFF_CAND);
  int*   kidx   = (int*)  (ws + OFF_KIDX);
  float* desc   = (float*)(ws + OFF_DESC);
  float* sbuf   = (float*)(ws + OFF_SBUF);
  float* Z      = (float*)(ws + OFF_Z);     // aliases SCORE region (score dead by then)
  float* ZT     = (float*)(ws + OFF_ZT);
  float* ubuf   = (float*)(ws + OFF_U);
  float* vbuf   = (float*)(ws + OFF_V);

  hipMemsetAsync(ws + OFF_V, 0, KP1 * sizeof(float), stream);

  gen_offsets_kernel<<<1, 256, 0, stream>>>(offs);
  detector_kernel<<<dim3(NBX, NBY, 2), dim3(16, 16), 0, stream>>>(img1, img2, score, smooth);
  nms_kernel<<<dim3(NBX, NBY, 2), dim3(16, 16), 0, stream>>>(score, cand);
  select_kernel<<<2, 1024, 0, stream>>>(cand, out, kidx);
  desc_kernel<<<dim3(KK, 2), 256, 0, stream>>>(smooth, kidx, offs, desc, sbuf);
  zbuild_kernel<<<dim3(33, 33), dim3(16, 16), 0, stream>>>(desc, sbuf, Z, ZT);
  for (int it = 0; it < 20; ++it) {
    lse_kernel<<<KP1, 256, 0, stream>>>(Z,  vbuf, ubuf);   // u update (rows)
    lse_kernel<<<KP1, 256, 0, stream>>>(ZT, ubuf, vbuf);   // v update (cols)
  }
  prob_kernel<<<KP1, 256, 0, stream>>>(Z, ubuf, vbuf, out + 2*KK*2);
}